// Round 7
// baseline (177.875 us; speedup 1.0000x reference)
//
#include <hip/hip_runtime.h>

// EquivariantGating: live math:
//   out0[z,w] = pw0*( sum_{u,v} s[z,u]s[z,v] W1[u,v,w] + INV_SQRT3*|v_z|^2*W4[w] )
//   out = (out0 @ WL)/16, split into two 512-vectors.
// GEMM M=512(z) N=256(w) K=65536(u,v); A[z,k]=s_u*s_v built on the fly (f16
// pk_mul), W1 staged f16. Block = 32u x 32v x 64w x 128z (z-split 4 -> grid
// 1024 = 4 blocks/CU, 50% occupancy ceiling). Depth-3 register prefetch
// (issue at r, consume at r+2) across lgkm-only barriers.

typedef __attribute__((ext_vector_type(8))) _Float16 f16x8;
typedef __attribute__((ext_vector_type(2))) _Float16 f16x2;
typedef __attribute__((ext_vector_type(4))) float f32x4;
typedef __attribute__((ext_vector_type(2))) int int2v;
typedef __attribute__((ext_vector_type(4))) int int4v;

#define LDS_S 16384            // 128 z-rows * 128B (64 f16 cols, 16B slots swizzled)
#define BP 80                  // B tile: bytes per w-row (64B data + 16B pad)
#define BSTEP 5120             // 64 w * BP  (one u-step)
#define LDS_TOTAL (LDS_S + 4 * BSTEP)   // 36864 B -> 4 blocks/CU

// f32 pair -> packed f16 bits (v_cvt_pkrtz_f16_f32)
__device__ __forceinline__ unsigned pkrtz(float a, float b) {
  return __builtin_bit_cast(unsigned, __builtin_amdgcn_cvt_pkrtz(a, b));
}
__device__ __forceinline__ int hbits(f16x2 h) {
  return __builtin_bit_cast(int, h);
}
__device__ __forceinline__ void barrier_lds() {
  // LDS-only drain: keep global prefetch loads (vmcnt) in flight across barrier
  asm volatile("s_waitcnt lgkmcnt(0)" ::: "memory");
  __builtin_amdgcn_s_barrier();
}

__global__ __launch_bounds__(256, 4) void eg_gemm(const float* __restrict__ s,
                                                  const float* __restrict__ W1,
                                                  float* __restrict__ out0) {
  extern __shared__ char smem[];
  char* sB = smem + LDS_S;

  const int bx = blockIdx.x;           // 1024 = 4 zh * 8 uc * 8 vc * 4 wt
  const int zh = bx >> 8;              // 0..3
  const int uvw = bx & 255;
  const int wt = uvw & 3, vc = (uvw >> 2) & 7, uc = uvw >> 5;
  const int u0 = uc * 32, v0 = vc * 32, w0 = wt * 64;

  const int t = threadIdx.x;           // 256 = 4 waves
  const int lane = t & 63;
  const int wid = t >> 6;
  const int l15 = lane & 15;
  const int g = lane >> 4;

  // ---- stage s tile (f16): 128 z x 64 cols (u-chunk 0..31, v-chunk 32..63)
  // row = 128B = 8 slots of 16B; slot swizzled by (zl&7)
  for (int j = 0; j < 8; ++j) {
    int id = j * 256 + t;              // 0..2047
    int zl = id >> 4;                  // 0..127
    int c4 = id & 15;
    int srccol = (c4 < 8) ? (u0 + (c4 << 2)) : (v0 + ((c4 - 8) << 2));
    const float4 f = *(const float4*)(s + (zh * 128 + zl) * 256 + srccol);
    int slot = c4 >> 1;
    char* dst = smem + zl * 128 + (((slot ^ (zl & 7)) << 4) | ((c4 & 1) << 3));
    *(int2v*)dst = int2v{(int)pkrtz(f.x, f.y), (int)pkrtz(f.z, f.w)};
  }

  // ---- B staging setup: thread owns (w = t&63, v-quads vg and vg+4)
  const int wB = t & 63;
  const int vg = t >> 6;               // 0..3
  const int hsw = (wB >> 3) & 7;
  const int sl0 = (vg ^ hsw) << 3;
  const int sl1 = ((vg + 4) ^ hsw) << 3;
  const float* gB = W1 + (size_t)u0 * 65536 + (v0 + vg * 4) * 256 + w0 + wB;

  float pf0[16], pf1[16];              // two prefetch sets (one round each)

#define ISSUE_TO(dst, usbase)                                               \
  do {                                                                      \
    const float* q0_ = gB + (size_t)(usbase) * 65536;                       \
    dst[0] = q0_[0];          dst[1] = q0_[256];                            \
    dst[2] = q0_[512];        dst[3] = q0_[768];                            \
    dst[4] = q0_[4096];       dst[5] = q0_[4096 + 256];                     \
    dst[6] = q0_[4096 + 512]; dst[7] = q0_[4096 + 768];                     \
    const float* q1_ = q0_ + 65536;                                         \
    dst[8] = q1_[0];           dst[9] = q1_[256];                           \
    dst[10] = q1_[512];        dst[11] = q1_[768];                          \
    dst[12] = q1_[4096];       dst[13] = q1_[4096 + 256];                   \
    dst[14] = q1_[4096 + 512]; dst[15] = q1_[4096 + 768];                   \
  } while (0)

#define WRITE_FROM(src, dst0_)                                              \
  do {                                                                      \
    char* d0_ = (dst0_);                                                    \
    *(int2v*)(d0_ + wB * BP + sl0) =                                        \
        int2v{(int)pkrtz(src[0], src[1]), (int)pkrtz(src[2], src[3])};      \
    *(int2v*)(d0_ + wB * BP + sl1) =                                        \
        int2v{(int)pkrtz(src[4], src[5]), (int)pkrtz(src[6], src[7])};      \
    char* d1_ = d0_ + BSTEP;                                                \
    *(int2v*)(d1_ + wB * BP + sl0) =                                        \
        int2v{(int)pkrtz(src[8], src[9]), (int)pkrtz(src[10], src[11])};    \
    *(int2v*)(d1_ + wB * BP + sl1) =                                        \
        int2v{(int)pkrtz(src[12], src[13]), (int)pkrtz(src[14], src[15])};  \
  } while (0)

  // ---- prologue: round 0 -> buf0 directly; pf0 <- round 1; pf1 <- round 2
  ISSUE_TO(pf0, 0);
  WRITE_FROM(pf0, sB);
  ISSUE_TO(pf0, 2);
  ISSUE_TO(pf1, 4);
  barrier_lds();

  // ---- hoist sv fragments (v-chunk is K-loop invariant): 8 f16 per mf
  const int swz = l15 & 7;
  int4v sv[2];
#pragma unroll
  for (int mf = 0; mf < 2; ++mf) {
    const char* p = smem + (wid * 32 + mf * 16 + l15) * 128 + (((4 + g) ^ swz) << 4);
    sv[mf] = *(const int4v*)p;
  }

  // B-frag read addresses (per nf): slot-XORed
  int baddr[4];
#pragma unroll
  for (int nf = 0; nf < 4; ++nf) {
    int w = nf * 16 + l15;
    baddr[nf] = w * BP + (((2 * g) ^ ((w >> 3) & 7)) << 3);
  }

  f32x4 acc[2][4];
#pragma unroll
  for (int a = 0; a < 2; ++a)
#pragma unroll
    for (int b = 0; b < 4; ++b) acc[a][b] = 0.f;

  // ---- main loop: 8 groups (q) x 2 rounds (rr) x 2 steps (p); us = 4q+2rr+p
  for (int q = 0; q < 8; ++q) {
    // su for us in [4q,4q+4): b64 per mf (u-cols, 16B slot = 8 cols)
    int2v sur[2];
#pragma unroll
    for (int mf = 0; mf < 2; ++mf) {
      const char* p = smem + (wid * 32 + mf * 16 + l15) * 128 +
                      ((((q >> 1) ^ swz) << 4) | ((q & 1) << 3));
      sur[mf] = *(const int2v*)p;
    }
#pragma unroll
    for (int rr = 0; rr < 2; ++rr) {
      const int r = 2 * q + rr;                 // round 0..15
      const char* bufc = sB + rr * (2 * BSTEP); // round r computes buf[r&1]
      char* bufn = sB + (rr ^ 1) * (2 * BSTEP);
#pragma unroll
      for (int p = 0; p < 2; ++p) {
        // A fragments: af[k] = f16(su * sv[k]) via v_pk_mul_f16
        f16x8 afr[2];
#pragma unroll
        for (int mf = 0; mf < 2; ++mf) {
          unsigned dw = (unsigned)sur[mf][rr];
          unsigned s2 = __builtin_amdgcn_perm(dw, dw, p ? 0x03020302u : 0x01000100u);
          f16x2 su2 = __builtin_bit_cast(f16x2, s2);
          int4v af;
#pragma unroll
          for (int jj = 0; jj < 4; ++jj) {
            f16x2 pv = __builtin_bit_cast(f16x2, (unsigned)sv[mf][jj]);
            f16x2 pr = su2 * pv;
            af[jj] = hbits(pr);
          }
          afr[mf] = __builtin_bit_cast(f16x8, af);
        }
        const char* bp = bufc + p * BSTEP;
#pragma unroll
        for (int nf = 0; nf < 4; ++nf) {
          int2v d0 = *(const int2v*)(bp + baddr[nf]);
          int2v d1 = *(const int2v*)(bp + (baddr[nf] ^ 8));
          int4v bf4 = int4v{d0[0], d0[1], d1[0], d1[1]};
          f16x8 bfr = __builtin_bit_cast(f16x8, bf4);
#pragma unroll
          for (int mf = 0; mf < 2; ++mf)
            acc[mf][nf] =
                __builtin_amdgcn_mfma_f32_16x16x32_f16(afr[mf], bfr, acc[mf][nf], 0, 0, 0);
        }
      }
      // pf[r&1] holds round r+1 data (issued at r-2); write LDS for r+1,
      // then reload pf[r&1] with round r+3 (consumed at r+2 -> 2-round flight)
      if (r < 15) {
        if (rr == 0) WRITE_FROM(pf0, bufn); else WRITE_FROM(pf1, bufn);
      }
      if (r <= 12) {
        if (rr == 0) ISSUE_TO(pf0, 2 * (r + 3)); else ISSUE_TO(pf1, 2 * (r + 3));
      }
      if (r < 15) barrier_lds();
    }
  }

  // ---- epilogue: atomic accumulate (C/D: col=lane&15, row=4*(lane>>4)+r),
  // nf issue order rotated per-block to de-hotspot colliding (uc,vc) blocks
  const int rot = (uc ^ vc) & 3;
#pragma unroll
  for (int mf = 0; mf < 2; ++mf)
#pragma unroll
    for (int nf = 0; nf < 4; ++nf) {
      const int nfr = (nf + rot) & 3;
#pragma unroll
      for (int rI = 0; rI < 4; ++rI) {
        int z = zh * 128 + wid * 32 + mf * 16 + g * 4 + rI;
        int w = w0 + nfr * 16 + l15;
        atomicAdd(out0 + z * 256 + w, acc[mf][nfr][rI]);
      }
    }
}

// Per z: add W4 term, scale by pw0, apply WL/16. One block (64 lanes) per z.
__global__ void eg_finish(const float* __restrict__ vec,
                          const float* __restrict__ W4,
                          const float* __restrict__ WL,
                          const float* __restrict__ acc,
                          float* __restrict__ out) {
  const int z = blockIdx.x;
  const int lane = threadIdx.x;
  float v0 = vec[z * 3 + 0], v1 = vec[z * 3 + 1], v2 = vec[z * 3 + 2];
  const float b = 0.57735026918962576f * (v0 * v0 + v1 * v1 + v2 * v2);
  float a0 = 0.f, a1 = 0.f;
#pragma unroll
  for (int j = 0; j < 4; ++j) {
    int w = j * 64 + lane;
    float o = acc[z * 256 + w] + b * W4[w];
    a0 += o * WL[2 * w];
    a1 += o * WL[2 * w + 1];
  }
#pragma unroll
  for (int off = 32; off > 0; off >>= 1) {
    a0 += __shfl_xor(a0, off);
    a1 += __shfl_xor(a1, off);
  }
  if (lane == 0) {
    // SCALE = pw0/16 = 1/(16*sqrt(65537))
    out[z] = 2.4413876e-04f * a0;
    out[512 + z] = 2.4413876e-04f * a1;
  }
}

extern "C" void kernel_launch(void* const* d_in, const int* in_sizes, int n_in,
                              void* d_out, int out_size, void* d_ws, size_t ws_size,
                              hipStream_t stream) {
  const float* vectors = (const float*)d_in[0];
  const float* scalars = (const float*)d_in[1];
  const float* W1 = (const float*)d_in[2];
  const float* W4 = (const float*)d_in[7];
  const float* WL = (const float*)d_in[8];
  float* out = (float*)d_out;
  float* acc = (float*)d_ws;  // 512*256 fp32 accumulator (512 KB)

  (void)hipMemsetAsync(acc, 0, 512 * 256 * sizeof(float), stream);
  eg_gemm<<<1024, 256, LDS_TOTAL, stream>>>(scalars, W1, acc);
  eg_finish<<<512, 64, 0, stream>>>(vectors, W4, WL, acc, out);
}